// Round 2
// baseline (285.925 us; speedup 1.0000x reference)
//
#include <hip/hip_runtime.h>
#include <math.h>

// Kobayashi dendrite single timestep, B=4, H=W=2048, fp32, periodic BCs.
// Fused single kernel: LDS-staged phi tile (halo 2) -> prod_mat1/2 + eps^2
// in LDS (halo 1) -> central diffs + outputs. Trig for epsilon eliminated
// via multiple-angle identities (cos/sin of 6*theta from phidx,phidy).

#define Bz 4
#define Hd 2048
#define Wd 2048
#define TX 64
#define TY 32
#define PW (TX + 4)   // 68: staged phi width
#define PH (TY + 4)   // 36: staged phi height
#define QW (TX + 2)   // 66: prod-mat width (halo 1)
#define QH (TY + 2)   // 34

#define INV2D   16.6666666666667f   // 1/(2*0.03)
#define INVD2   1111.11111111111f   // 1/0.03^2
#define DT_TAU  0.333333333333333f  // 1e-4 / 3e-4
#define DTc     1e-4f
#define KAPPAc  1.8f
#define EPSB    0.01f
#define DELTAc  0.02f
#define ANISOc  6.0f
#define A_PI    0.2864788975654116f // 0.9/pi
#define GAMMAc  10.0f
#define TEQc    1.0f
#define C6T0    0.3623577544766736f // cos(1.2)
#define S6T0    0.9320390859672263f // sin(1.2)

__global__ __launch_bounds__(256) void dendrite_step(
    const float* __restrict__ phi, const float* __restrict__ tempr,
    float* __restrict__ out_phi, float* __restrict__ out_tempr)
{
    __shared__ float sphi[PH * PW];
    __shared__ float sp1[QH * QW];
    __shared__ float sp2[QH * QW];
    __shared__ float se2[QH * QW];

    const int tid = threadIdx.x;
    const int x0 = blockIdx.x * TX;
    const int y0 = blockIdx.y * TY;
    const int base = blockIdx.z * (Hd * Wd);

    // ---- Phase 1: stage phi tile with halo 2 (periodic wrap) ----
    for (int i = tid; i < PH * PW; i += 256) {
        int r = i / PW;
        int c = i - r * PW;
        int gy = (y0 + r - 2) & (Hd - 1);
        int gx = (x0 + c - 2) & (Wd - 1);
        sphi[i] = phi[base + gy * Wd + gx];
    }
    __syncthreads();

    // ---- Phase 2: prod_mat1, prod_mat2, eps^2 on halo-1 region ----
    for (int i = tid; i < QH * QW; i += 256) {
        int r = i / QW;
        int c = i - r * QW;
        int p = (r + 1) * PW + (c + 1);
        float phidx = (sphi[p + 1]  - sphi[p - 1])  * INV2D;
        float phidy = (sphi[p + PW] - sphi[p - PW]) * INV2D;

        // cos(theta), sin(theta) without atan2; atan2(0,0)=0 convention
        float r2 = phidx * phidx + phidy * phidy;
        float rinv = (r2 > 0.0f) ? rsqrtf(r2) : 0.0f;
        float ct = (r2 > 0.0f) ? phidx * rinv : 1.0f;
        float st = phidy * rinv;

        // 6x angle via doubling/addition
        float c2 = ct * ct - st * st;
        float s2 = 2.0f * ct * st;
        float c4 = c2 * c2 - s2 * s2;
        float s4 = 2.0f * c2 * s2;
        float c6 = c4 * c2 - s4 * s2;
        float s6 = s4 * c2 + c4 * s2;

        // cos/sin(6*theta - 6*theta0)
        float cosA = c6 * C6T0 + s6 * S6T0;
        float sinA = s6 * C6T0 - c6 * S6T0;

        float eps  = EPSB * (1.0f + DELTAc * cosA);
        float epsd = -EPSB * ANISOc * DELTAc * sinA;
        float ee   = eps * epsd;

        sp1[i] = ee * phidx;
        sp2[i] = -ee * phidy;
        se2[i] = eps * eps;
    }
    __syncthreads();

    // ---- Phase 3: outputs. tid -> (tx, ty) with one wave per row. ----
    const int tx = tid & 63;
    const int ty0 = tid >> 6;   // 0..3

    for (int k = 0; k < TY / 4; ++k) {
        int y = ty0 + k * 4;
        int q = (y + 1) * QW + (tx + 1);
        int p = (y + 2) * PW + (tx + 2);

        float term1 = (sp1[q + QW] - sp1[q - QW]) * INV2D;  // d/dy prod1
        float term2 = (sp2[q + 1]  - sp2[q - 1])  * INV2D;  // d/dx prod2

        float phic = sphi[p];
        float lap_phi = (sphi[p + 1] + sphi[p - 1] - 2.0f * phic) * INVD2
                      + (sphi[p + PW] + sphi[p - PW] - 2.0f * phic) * INVD2;

        int gy = y0 + y;
        int gx = x0 + tx;
        int gxp = (gx + 1) & (Wd - 1);
        int gxm = (gx - 1) & (Wd - 1);
        int gyp = (gy + 1) & (Hd - 1);
        int gym = (gy - 1) & (Hd - 1);
        int rowb = base + gy * Wd;

        float tc = tempr[rowb + gx];
        float lap_t = (tempr[rowb + gxp] + tempr[rowb + gxm] - 2.0f * tc) * INVD2
                    + (tempr[base + gyp * Wd + gx] + tempr[base + gym * Wd + gx]
                       - 2.0f * tc) * INVD2;

        float m = A_PI * atanf(GAMMAc * (TEQc - tc));
        float dphi = DT_TAU * (term1 + term2 + se2[q] * lap_phi
                               + phic * (1.0f - phic) * (phic - 0.5f + m));

        int gidx = rowb + gx;
        out_phi[gidx] = phic + dphi;
        out_tempr[gidx] = tc + DTc * lap_t + KAPPAc * dphi;
    }
}

extern "C" void kernel_launch(void* const* d_in, const int* in_sizes, int n_in,
                              void* d_out, int out_size, void* d_ws, size_t ws_size,
                              hipStream_t stream) {
    const float* phi = (const float*)d_in[0];
    const float* tempr = (const float*)d_in[1];
    float* out_phi = (float*)d_out;
    float* out_tempr = out_phi + (size_t)Bz * Hd * Wd;

    dim3 grid(Wd / TX, Hd / TY, Bz);
    dendrite_step<<<grid, 256, 0, stream>>>(phi, tempr, out_phi, out_tempr);
}

// Round 3
// 245.721 us; speedup vs baseline: 1.1636x; 1.1636x over previous
//
#include <hip/hip_runtime.h>
#include <hip/hip_fp16.h>
#include <math.h>

// Kobayashi dendrite single timestep, B=4, H=W=2048, fp32, periodic BCs.
// Round 3: fp16 LDS staging (scaled x4096) -> 18.4 KB LDS -> 8 blocks/CU;
// paired float2 phase-1 loads; 2-cell phase 2 with half2 b64 LDS traffic;
// rolling-register phase 3 (consecutive-row sweep: phi col, sp1, tempr rows).

#define Bz 4
#define Hd 2048
#define Wd 2048
#define TX 64
#define TY 32
#define PW 68          // phi tile width  (halo 2)
#define PH 36          // phi tile height (halo 2)
#define QW 66          // prod tile width  (halo 1)
#define QH 34          // prod tile height (halo 1)

#define INV2D   16.6666666666667f   // 1/(2*0.03)
#define INVD2   1111.11111111111f   // 1/0.03^2
#define DT_TAU  0.333333333333333f  // 1e-4 / 3e-4
#define DTc     1e-4f
#define KAPPAc  1.8f
#define EPSB    0.01f
#define DELTAc  0.02f
#define ANISOc  6.0f
#define A_PI    0.2864788975654116f // 0.9/pi
#define GAMMAc  10.0f
#define TEQc    1.0f
#define C6T0    0.3623577544766736f // cos(1.2)
#define S6T0    0.9320390859672263f // sin(1.2)
#define SC      4096.0f             // fp16 scale (keeps prod/eps^2 normal-range)
#define ISC     (1.0f/4096.0f)

__device__ __forceinline__ void prod_chain(float phidx, float phidy,
                                           float& sp1s, float& sp2s, float& se2s)
{
    float r2 = phidx * phidx + phidy * phidy;
    float rinv = (r2 > 0.0f) ? rsqrtf(r2) : 0.0f;
    float ct = (r2 > 0.0f) ? phidx * rinv : 1.0f;
    float st = phidy * rinv;
    float c2 = ct * ct - st * st;
    float s2 = 2.0f * ct * st;
    float c4 = c2 * c2 - s2 * s2;
    float s4 = 2.0f * c2 * s2;
    float c6 = c4 * c2 - s4 * s2;
    float s6 = s4 * c2 + c4 * s2;
    float cosA = c6 * C6T0 + s6 * S6T0;
    float sinA = s6 * C6T0 - c6 * S6T0;
    float eps  = EPSB * (1.0f + DELTAc * cosA);
    float epsd = -EPSB * ANISOc * DELTAc * sinA;
    float eesc = eps * epsd * SC;
    sp1s = eesc * phidx;
    sp2s = -eesc * phidy;
    se2s = eps * eps * SC;
}

__global__ __launch_bounds__(256, 8) void dendrite_step(
    const float* __restrict__ phi, const float* __restrict__ tempr,
    float* __restrict__ out_phi, float* __restrict__ out_tempr)
{
    __shared__ __half2 sphi2[PH * PW / 2];   // 36*34 half2 = 4896 B
    __shared__ __half2 spk[QH * QW];         // .x=sp1*SC .y=sp2*SC, 8976 B
    __shared__ __half2 se2_2[QH * QW / 2];   // eps^2*SC pairs, 4488 B

    const int tid = threadIdx.x;
    const int x0 = blockIdx.x * TX;
    const int y0 = blockIdx.y * TY;
    const int base = blockIdx.z * (Hd * Wd);

    // ---- Phase 1: stage phi tile (halo 2) as fp16, float2 global loads ----
    // Pairs never straddle the periodic wrap: x0 even, pair-start offsets even.
    for (int i = tid; i < PH * PW / 2; i += 256) {
        int r = i / (PW / 2);
        int c2 = i - r * (PW / 2);
        int gy = (y0 + r - 2) & (Hd - 1);
        int gx = (x0 + 2 * c2 - 2) & (Wd - 1);
        float2 v = *(const float2*)(phi + base + gy * Wd + gx);
        sphi2[i] = __floats2half2_rn(v.x, v.y);
    }
    __syncthreads();

    // ---- Phase 2: prod_mat1/2 + eps^2 on halo-1 region, 2 cells/thread ----
    const __half* sph = (const __half*)sphi2;
    for (int i = tid; i < QH * (QW / 2); i += 256) {
        int r = i / (QW / 2);
        int c2 = i - r * (QW / 2);
        int cQ = 2 * c2;            // Q col of first cell
        int pr = r + 1;             // phi row
        int rowc = pr * (PW / 2) + c2;
        __half2 A = sphi2[rowc];
        __half2 Bv = sphi2[rowc + 1];
        __half2 U0 = sphi2[rowc - PW / 2];
        __half2 U1 = sphi2[rowc - PW / 2 + 1];
        __half2 D0 = sphi2[rowc + PW / 2];
        __half2 D1 = sphi2[rowc + PW / 2 + 1];

        float f0 = __low2float(A),  f1 = __high2float(A);
        float f2 = __low2float(Bv), f3 = __high2float(Bv);

        float sp1a, sp2a, se2a, sp1b, sp2b, se2b;
        prod_chain((f2 - f0) * INV2D,
                   (__high2float(D0) - __high2float(U0)) * INV2D,
                   sp1a, sp2a, se2a);
        prod_chain((f3 - f1) * INV2D,
                   (__low2float(D1) - __low2float(U1)) * INV2D,
                   sp1b, sp2b, se2b);

        int q = r * QW + cQ;
        spk[q]     = __floats2half2_rn(sp1a, sp2a);
        spk[q + 1] = __floats2half2_rn(sp1b, sp2b);
        se2_2[r * (QW / 2) + c2] = __floats2half2_rn(se2a, se2b);
    }
    __syncthreads();

    // ---- Phase 3: rolling-register sweep, 8 consecutive rows per thread ----
    const __half* se2h = (const __half*)se2_2;
    const int tx = tid & 63;
    const int tg = tid >> 6;          // 0..3
    const int ys = tg * 8;            // first local row
    const int col = tx + 2;           // phi-tile col
    const int gx = x0 + tx;
    const int gxm = (gx - 1) & (Wd - 1);
    const int gxp = (gx + 1) & (Wd - 1);

    // phi center column regs (phi rows ys+1, ys+2)
    float pm = __half2float(sph[(ys + 1) * PW + col]);
    float pc_ = __half2float(sph[(ys + 2) * PW + col]);
    // sp1 regs (Q rows ys, ys+1)
    float s1m = __low2float(spk[ys * QW + tx + 1]);
    float s1c = __low2float(spk[(ys + 1) * QW + tx + 1]);
    // tempr regs: prev center; current row (l,c,r)
    float tm  = tempr[base + ((y0 + ys - 1) & (Hd - 1)) * Wd + gx];
    {
        int rb = base + (y0 + ys) * Wd;
        // current row loaded below via first-iteration shift pattern
        (void)rb;
    }
    int rb0 = base + (y0 + ys) * Wd;
    float tcl = tempr[rb0 + gxm];
    float tcc = tempr[rb0 + gx];
    float tcr = tempr[rb0 + gxp];

    for (int k = 0; k < 8; ++k) {
        int y = ys + k;               // local row
        int qrow = y + 1;
        int prow = y + 2;

        float pp = __half2float(sph[(prow + 1) * PW + col]);
        float pl = __half2float(sph[prow * PW + col - 1]);
        float prr = __half2float(sph[prow * PW + col + 1]);
        float lap_phi = (pl + prr - 2.0f * pc_) * INVD2
                      + (pm + pp - 2.0f * pc_) * INVD2;

        float s1p = __low2float(spk[(qrow + 1) * QW + tx + 1]);
        float term1 = (s1p - s1m) * (INV2D * ISC);
        float sp2l = __high2float(spk[qrow * QW + tx]);
        float sp2r = __high2float(spk[qrow * QW + tx + 2]);
        float term2 = (sp2r - sp2l) * (INV2D * ISC);
        float e2 = __half2float(se2h[qrow * QW + tx + 1]) * ISC;

        // next tempr row (y+1 may wrap at the bottom edge)
        int rbp = base + ((y0 + y + 1) & (Hd - 1)) * Wd;
        float tpl = tempr[rbp + gxm];
        float tpc = tempr[rbp + gx];
        float tpr = tempr[rbp + gxp];

        float lap_t = (tcl + tcr - 2.0f * tcc) * INVD2
                    + (tm + tpc - 2.0f * tcc) * INVD2;

        float m = A_PI * atanf(GAMMAc * (TEQc - tcc));
        float dphi = DT_TAU * (term1 + term2 + e2 * lap_phi
                               + pc_ * (1.0f - pc_) * (pc_ - 0.5f + m));

        int gidx = base + (y0 + y) * Wd + gx;
        out_phi[gidx] = pc_ + dphi;
        out_tempr[gidx] = tcc + DTc * lap_t + KAPPAc * dphi;

        // roll registers
        pm = pc_; pc_ = pp;
        s1m = s1c; s1c = s1p;
        tm = tcc; tcl = tpl; tcc = tpc; tcr = tpr;
    }
}

extern "C" void kernel_launch(void* const* d_in, const int* in_sizes, int n_in,
                              void* d_out, int out_size, void* d_ws, size_t ws_size,
                              hipStream_t stream) {
    const float* phi = (const float*)d_in[0];
    const float* tempr = (const float*)d_in[1];
    float* out_phi = (float*)d_out;
    float* out_tempr = out_phi + (size_t)Bz * Hd * Wd;

    dim3 grid(Wd / TX, Hd / TY, Bz);
    dendrite_step<<<grid, 256, 0, stream>>>(phi, tempr, out_phi, out_tempr);
}